// Round 4
// baseline (467.302 us; speedup 1.0000x reference)
//
#include <hip/hip_runtime.h>

// Problem constants (fixed by the reference's config)
#define HH 480
#define WW 640
#define NN (HH * WW)
#define BB 8
#define PP 4
#define EPS 1e-9f

// Tiled-staging geometry (real pipeline)
#define TS 48
#define RR 12
#define EXT (TS + 2 * RR)        // 72
#define EXT2 (EXT * EXT)
#define SFLOATS (EXT2 * 3)       // 15552 floats = 62208 B LDS
#define NTX ((WW + TS - 1) / TS) // 14
#define NTY ((HH + TS - 1) / TS) // 10
#define NTILES (NTX * NTY)       // 140

// Ablation-C geometry (small tile, high occupancy)
#define TS3 24
#define EXT3 (TS3 + 2 * RR)      // 48
#define SFLOATS3 (EXT3 * EXT3 * 3) // 6912 floats = 27648 B LDS
#define NTX3 ((WW + TS3 - 1) / TS3) // 27
#define NTY3 ((HH + TS3 - 1) / TS3) // 20

__device__ __forceinline__ void atomic_add_f32(float* p, float v) {
    unsafeAtomicAdd(p, v);
}

// ---------------- real pipeline (unchanged from R2) ----------------

__global__ __launch_bounds__(256)
void splat_stage(const float* __restrict__ fx_all,
                 const float* __restrict__ fy_all,
                 const int* __restrict__ i_ptr,
                 const int* __restrict__ tref_ptr,
                 float* __restrict__ S,
                 float* __restrict__ Fw,
                 float* __restrict__ Fwy,
                 float* __restrict__ Fwx) {
    __shared__ float sacc[SFLOATS];
    const int tid = threadIdx.x;
    for (int e = tid; e < SFLOATS; e += 256) sacc[e] = 0.0f;
    __syncthreads();

    const int txi = blockIdx.x, tyi = blockIdx.y, b = blockIdx.z;
    const int tx0 = txi * TS, ty0 = tyi * TS;
    const int i = *i_ptr;
    const float dt = (float)(*tref_ptr - i);
    const float* __restrict__ fxp = fx_all + (size_t)(b * PP + i) * NN;
    const float* __restrict__ fyp = fy_all + (size_t)(b * PP + i) * NN;

    for (int sp = tid; sp < TS * TS; sp += 256) {
        int sy = sp / TS, sx = sp - sy * TS;
        int gy = ty0 + sy, gx = tx0 + sx;
        if (gy >= HH || gx >= WW) continue;
        int p = gy * WW + gx;
        float fx = fxp[p], fy = fyp[p];
        float wyf = (float)gy + dt * fy;
        float wxf = (float)gx + dt * fx;
        if (!(wyf >= 0.0f && wyf <= (float)(HH - 1) &&
              wxf >= 0.0f && wxf <= (float)(WW - 1))) continue;
        float tyf = floorf(wyf), lxf = floorf(wxf);
        float fry = wyf - tyf, frx = wxf - lxf;
        int iy0 = (int)tyf, ix0 = (int)lxf;
        float wts[4] = {(1.0f - fry) * (1.0f - frx),
                        (1.0f - fry) * frx,
                        fry * (1.0f - frx),
                        fry * frx};
#pragma unroll
        for (int k = 0; k < 4; ++k) {
            int iy = iy0 + (k >> 1), ix = ix0 + (k & 1);
            if (iy >= HH || ix >= WW) continue;
            float w = wts[k];
            int ly = iy - (ty0 - RR), lx = ix - (tx0 - RR);
            if ((unsigned)ly < (unsigned)EXT && (unsigned)lx < (unsigned)EXT) {
                int e = (ly * EXT + lx) * 3;
                atomic_add_f32(&sacc[e + 0], w);
                atomic_add_f32(&sacc[e + 1], w * fy);
                atomic_add_f32(&sacc[e + 2], w * fx);
            } else {
                int fi = b * NN + iy * WW + ix;
                atomic_add_f32(&Fw[fi], w);
                atomic_add_f32(&Fwy[fi], w * fy);
                atomic_add_f32(&Fwx[fi], w * fx);
            }
        }
    }
    __syncthreads();

    float* __restrict__ St = S + (size_t)(b * NTILES + tyi * NTX + txi) * SFLOATS;
    for (int e = tid; e < SFLOATS; e += 256) St[e] = sacc[e];
}

// ---------------- ablation A: plain ds_write instead of atomics ----------------

__global__ __launch_bounds__(256)
void ablA_write(const float* __restrict__ fx_all,
                const float* __restrict__ fy_all,
                const int* __restrict__ i_ptr,
                const int* __restrict__ tref_ptr,
                float* __restrict__ S) {
    __shared__ float sacc[SFLOATS];
    const int tid = threadIdx.x;
    for (int e = tid; e < SFLOATS; e += 256) sacc[e] = 0.0f;
    __syncthreads();

    const int txi = blockIdx.x, tyi = blockIdx.y, b = blockIdx.z;
    const int tx0 = txi * TS, ty0 = tyi * TS;
    const int i = *i_ptr;
    const float dt = (float)(*tref_ptr - i);
    const float* __restrict__ fxp = fx_all + (size_t)(b * PP + i) * NN;
    const float* __restrict__ fyp = fy_all + (size_t)(b * PP + i) * NN;

    for (int sp = tid; sp < TS * TS; sp += 256) {
        int sy = sp / TS, sx = sp - sy * TS;
        int gy = ty0 + sy, gx = tx0 + sx;
        if (gy >= HH || gx >= WW) continue;
        int p = gy * WW + gx;
        float fx = fxp[p], fy = fyp[p];
        float wyf = (float)gy + dt * fy;
        float wxf = (float)gx + dt * fx;
        if (!(wyf >= 0.0f && wyf <= (float)(HH - 1) &&
              wxf >= 0.0f && wxf <= (float)(WW - 1))) continue;
        float tyf = floorf(wyf), lxf = floorf(wxf);
        float fry = wyf - tyf, frx = wxf - lxf;
        int iy0 = (int)tyf, ix0 = (int)lxf;
        float wts[4] = {(1.0f - fry) * (1.0f - frx),
                        (1.0f - fry) * frx,
                        fry * (1.0f - frx),
                        fry * frx};
#pragma unroll
        for (int k = 0; k < 4; ++k) {
            int iy = iy0 + (k >> 1), ix = ix0 + (k & 1);
            if (iy >= HH || ix >= WW) continue;
            float w = wts[k];
            int ly = iy - (ty0 - RR), lx = ix - (tx0 - RR);
            if ((unsigned)ly < (unsigned)EXT && (unsigned)lx < (unsigned)EXT) {
                int e = (ly * EXT + lx) * 3;
                sacc[e + 0] = w;           // plain write (WRONG results, scratch only)
                sacc[e + 1] = w * fy;
                sacc[e + 2] = w * fx;
            }
        }
    }
    __syncthreads();

    float* __restrict__ St = S + (size_t)(b * NTILES + tyi * NTX + txi) * SFLOATS;
    for (int e = tid; e < SFLOATS; e += 256) St[e] = sacc[e];
}

// ---------------- ablation B: only k=0 neighbor (1/4 of the atomics) ----------------

__global__ __launch_bounds__(256)
void ablB_quarter(const float* __restrict__ fx_all,
                  const float* __restrict__ fy_all,
                  const int* __restrict__ i_ptr,
                  const int* __restrict__ tref_ptr,
                  float* __restrict__ S) {
    __shared__ float sacc[SFLOATS];
    const int tid = threadIdx.x;
    for (int e = tid; e < SFLOATS; e += 256) sacc[e] = 0.0f;
    __syncthreads();

    const int txi = blockIdx.x, tyi = blockIdx.y, b = blockIdx.z;
    const int tx0 = txi * TS, ty0 = tyi * TS;
    const int i = *i_ptr;
    const float dt = (float)(*tref_ptr - i);
    const float* __restrict__ fxp = fx_all + (size_t)(b * PP + i) * NN;
    const float* __restrict__ fyp = fy_all + (size_t)(b * PP + i) * NN;

    for (int sp = tid; sp < TS * TS; sp += 256) {
        int sy = sp / TS, sx = sp - sy * TS;
        int gy = ty0 + sy, gx = tx0 + sx;
        if (gy >= HH || gx >= WW) continue;
        int p = gy * WW + gx;
        float fx = fxp[p], fy = fyp[p];
        float wyf = (float)gy + dt * fy;
        float wxf = (float)gx + dt * fx;
        if (!(wyf >= 0.0f && wyf <= (float)(HH - 1) &&
              wxf >= 0.0f && wxf <= (float)(WW - 1))) continue;
        float tyf = floorf(wyf), lxf = floorf(wxf);
        float fry = wyf - tyf, frx = wxf - lxf;
        int iy0 = (int)tyf, ix0 = (int)lxf;
        float w = (1.0f - fry) * (1.0f - frx);
        int iy = iy0, ix = ix0;
        int ly = iy - (ty0 - RR), lx = ix - (tx0 - RR);
        if ((unsigned)ly < (unsigned)EXT && (unsigned)lx < (unsigned)EXT) {
            int e = (ly * EXT + lx) * 3;
            atomic_add_f32(&sacc[e + 0], w);
            atomic_add_f32(&sacc[e + 1], w * fy);
            atomic_add_f32(&sacc[e + 2], w * fx);
        }
    }
    __syncthreads();

    float* __restrict__ St = S + (size_t)(b * NTILES + tyi * NTX + txi) * SFLOATS;
    for (int e = tid; e < SFLOATS; e += 256) St[e] = sacc[e];
}

// ---------------- ablation C: small tile (27.6 KB LDS -> ~5 blocks/CU) ----------------

__global__ __launch_bounds__(256)
void ablC_small(const float* __restrict__ fx_all,
                const float* __restrict__ fy_all,
                const int* __restrict__ i_ptr,
                const int* __restrict__ tref_ptr,
                float* __restrict__ S) {
    __shared__ float sacc[SFLOATS3];
    const int tid = threadIdx.x;
    for (int e = tid; e < SFLOATS3; e += 256) sacc[e] = 0.0f;
    __syncthreads();

    const int txi = blockIdx.x, tyi = blockIdx.y, b = blockIdx.z;
    const int tx0 = txi * TS3, ty0 = tyi * TS3;
    const int i = *i_ptr;
    const float dt = (float)(*tref_ptr - i);
    const float* __restrict__ fxp = fx_all + (size_t)(b * PP + i) * NN;
    const float* __restrict__ fyp = fy_all + (size_t)(b * PP + i) * NN;

    for (int sp = tid; sp < TS3 * TS3; sp += 256) {
        int sy = sp / TS3, sx = sp - sy * TS3;
        int gy = ty0 + sy, gx = tx0 + sx;
        if (gy >= HH || gx >= WW) continue;
        int p = gy * WW + gx;
        float fx = fxp[p], fy = fyp[p];
        float wyf = (float)gy + dt * fy;
        float wxf = (float)gx + dt * fx;
        if (!(wyf >= 0.0f && wyf <= (float)(HH - 1) &&
              wxf >= 0.0f && wxf <= (float)(WW - 1))) continue;
        float tyf = floorf(wyf), lxf = floorf(wxf);
        float fry = wyf - tyf, frx = wxf - lxf;
        int iy0 = (int)tyf, ix0 = (int)lxf;
        float wts[4] = {(1.0f - fry) * (1.0f - frx),
                        (1.0f - fry) * frx,
                        fry * (1.0f - frx),
                        fry * frx};
#pragma unroll
        for (int k = 0; k < 4; ++k) {
            int iy = iy0 + (k >> 1), ix = ix0 + (k & 1);
            if (iy >= HH || ix >= WW) continue;
            float w = wts[k];
            int ly = iy - (ty0 - RR), lx = ix - (tx0 - RR);
            if ((unsigned)ly < (unsigned)EXT3 && (unsigned)lx < (unsigned)EXT3) {
                int e = (ly * EXT3 + lx) * 3;
                atomic_add_f32(&sacc[e + 0], w);
                atomic_add_f32(&sacc[e + 1], w * fy);
                atomic_add_f32(&sacc[e + 2], w * fx);
            }
        }
    }
    __syncthreads();

    // garbage flush into (reused) S scratch, wrapped to stay in bounds
    size_t tile_id = ((size_t)b * (NTX3 * NTY3) + tyi * NTX3 + txi) % ((size_t)BB * NTILES);
    float* __restrict__ St = S + tile_id * SFLOATS;
    for (int e = tid; e < SFLOATS3; e += 256) St[e] = sacc[e];
}

// ---------------- gather / fallback ----------------

__global__ __launch_bounds__(256)
void gather_finalize(const float* __restrict__ S,
                     const float* __restrict__ Fw,
                     const float* __restrict__ Fwy,
                     const float* __restrict__ Fwx,
                     float* __restrict__ out) {
    int t = blockIdx.x * blockDim.x + threadIdx.x;
    if (t >= BB * NN) return;
    int b = t / NN, p = t - b * NN;
    int y = p / WW, x = p - y * WW;

    float w = Fw[t], wy = Fwy[t], wx = Fwx[t];

    int ty_lo = y - (TS - 1 + RR);
    ty_lo = ty_lo > 0 ? (ty_lo + TS - 1) / TS : 0;
    int ty_hi = (y + RR) / TS; if (ty_hi > NTY - 1) ty_hi = NTY - 1;
    int tx_lo = x - (TS - 1 + RR);
    tx_lo = tx_lo > 0 ? (tx_lo + TS - 1) / TS : 0;
    int tx_hi = (x + RR) / TS; if (tx_hi > NTX - 1) tx_hi = NTX - 1;

    for (int tyi = ty_lo; tyi <= ty_hi; ++tyi) {
        int ly = y - (tyi * TS - RR);
        for (int txi = tx_lo; txi <= tx_hi; ++txi) {
            int lx = x - (txi * TS - RR);
            const float* __restrict__ St =
                S + (size_t)(b * NTILES + tyi * NTX + txi) * SFLOATS + (ly * EXT + lx) * 3;
            w  += St[0];
            wy += St[1];
            wx += St[2];
        }
    }
    float denom = w + EPS;
    out[t] = wx / denom;
    out[(size_t)BB * NN + t] = wy / denom;
}

__global__ void splat_kernel(const float* __restrict__ fx_all,
                             const float* __restrict__ fy_all,
                             const int* __restrict__ i_ptr,
                             const int* __restrict__ tref_ptr,
                             float* __restrict__ sum_w,
                             float* __restrict__ sum_wy,
                             float* __restrict__ sum_wx) {
    int t = blockIdx.x * blockDim.x + threadIdx.x;
    if (t >= BB * NN) return;
    int b = t / NN;
    int p = t - b * NN;
    int i = *i_ptr;
    float dt = (float)(*tref_ptr - i);
    const float fx = fx_all[(size_t)(b * PP + i) * NN + p];
    const float fy = fy_all[(size_t)(b * PP + i) * NN + p];
    float gy = (float)(p / WW);
    float gx = (float)(p - (p / WW) * WW);
    float wy = gy + dt * fy;
    float wx = gx + dt * fx;
    bool inside = (wy >= 0.0f) && (wy <= (float)(HH - 1)) &&
                  (wx >= 0.0f) && (wx <= (float)(WW - 1));
    if (!inside) return;
    float ty = floorf(wy);
    float lx = floorf(wx);
    int base = b * NN;
#pragma unroll
    for (int k = 0; k < 4; ++k) {
        float ny = ty + (float)(k >> 1);
        float nx = lx + (float)(k & 1);
        int iy = (int)ny;
        int ix = (int)nx;
        if (iy < 0 || iy >= HH || ix < 0 || ix >= WW) continue;
        float wgt_y = fminf(fmaxf(1.0f - fabsf(wy - ny), 0.0f), 1.0f);
        float wgt_x = fminf(fmaxf(1.0f - fabsf(wx - nx), 0.0f), 1.0f);
        float w = wgt_y * wgt_x;
        int fi = base + iy * WW + ix;
        atomic_add_f32(&sum_w[fi],  w);
        atomic_add_f32(&sum_wy[fi], w * fy);
        atomic_add_f32(&sum_wx[fi], w * fx);
    }
}

__global__ void finalize_kernel(const float* __restrict__ sum_w,
                                const float* __restrict__ sum_wy,
                                const float* __restrict__ sum_wx,
                                float* __restrict__ out) {
    int t = blockIdx.x * blockDim.x + threadIdx.x;
    if (t >= BB * NN) return;
    float denom = sum_w[t] + EPS;
    out[t]                   = sum_wx[t] / denom;
    out[(size_t)BB * NN + t] = sum_wy[t] / denom;
}

// ---------------- launch ----------------

extern "C" void kernel_launch(void* const* d_in, const int* in_sizes, int n_in,
                              void* d_out, int out_size, void* d_ws, size_t ws_size,
                              hipStream_t stream) {
    const float* fx_all = (const float*)d_in[0];
    const float* fy_all = (const float*)d_in[1];
    const int* i_ptr    = (const int*)d_in[2];
    const int* tref_ptr = (const int*)d_in[3];
    float* out = (float*)d_out;

    const size_t S_bytes = (size_t)BB * NTILES * SFLOATS * sizeof(float); // ~69.7 MB
    const size_t F_elems = (size_t)BB * NN;
    const size_t F_bytes = F_elems * 3 * sizeof(float);                   // ~29.5 MB

    if (ws_size >= S_bytes + F_bytes) {
        float* S   = (float*)d_ws;
        float* Fw  = (float*)((char*)d_ws + S_bytes);
        float* Fwy = Fw + F_elems;
        float* Fwx = Fwy + F_elems;

        // --- ablation experiments (results discarded; S fully overwritten below) ---
        ablA_write<<<dim3(NTX, NTY, BB), 256, 0, stream>>>(
            fx_all, fy_all, i_ptr, tref_ptr, S);
        ablB_quarter<<<dim3(NTX, NTY, BB), 256, 0, stream>>>(
            fx_all, fy_all, i_ptr, tref_ptr, S);
        ablC_small<<<dim3(NTX3, NTY3, BB), 256, 0, stream>>>(
            fx_all, fy_all, i_ptr, tref_ptr, S);

        // --- real pipeline (unchanged) ---
        hipMemsetAsync(Fw, 0, F_bytes, stream);
        splat_stage<<<dim3(NTX, NTY, BB), 256, 0, stream>>>(
            fx_all, fy_all, i_ptr, tref_ptr, S, Fw, Fwy, Fwx);
        int total = BB * NN;
        gather_finalize<<<(total + 255) / 256, 256, 0, stream>>>(S, Fw, Fwy, Fwx, out);
    } else {
        float* sum_w  = (float*)d_ws;
        float* sum_wy = sum_w + (size_t)BB * NN;
        float* sum_wx = sum_wy + (size_t)BB * NN;
        hipMemsetAsync(d_ws, 0, (size_t)3 * BB * NN * sizeof(float), stream);
        int total = BB * NN;
        int block = 256;
        int grid = (total + block - 1) / block;
        splat_kernel<<<grid, block, 0, stream>>>(fx_all, fy_all, i_ptr, tref_ptr,
                                                 sum_w, sum_wy, sum_wx);
        finalize_kernel<<<grid, block, 0, stream>>>(sum_w, sum_wy, sum_wx, out);
    }
}

// Round 5
// 215.160 us; speedup vs baseline: 2.1719x; 2.1719x over previous
//
#include <hip/hip_runtime.h>

// Problem constants (fixed by the reference's config)
#define HH 480
#define WW 640
#define NN (HH * WW)
#define BB 8
#define PP 4
#define EPS 1e-9f

// Output-tile geometry: each block owns a TW x TH OUTPUT tile and reads the
// source halo region around it. Image is exactly tiled: 640/64=10, 480/32=15.
#define TW 64
#define TH 32
#define HALO 12
#define RGW (TW + 2 * HALO)   // 88  source region width
#define RGH (TH + 2 * HALO)   // 56  source region height
#define RGN (RGW * RGH)       // 4928
#define TCELLS (TW * TH)      // 2048
#define NBX (WW / TW)         // 10
#define NBY (HH / TH)         // 15

__device__ __forceinline__ void atomic_add_f32(float* p, float v) {
    unsafeAtomicAdd(p, v);
}

// ---------------- main splat: output-tile centric ----------------
// Rule: block B (tile T) processes all sources s with dist_inf(s,T) <= HALO.
// For each bilinear neighbor N of s: if N in T -> LDS atomic add.
// Coverage: the (s,N) pair is LDS-added exactly once iff dist_inf(s,tile(N))
// <= HALO. Otherwise the block OWNING s (s interior) adds it to global F.
__global__ __launch_bounds__(256)
void splat_tile(const float* __restrict__ fx_all,
                const float* __restrict__ fy_all,
                const int* __restrict__ i_ptr,
                const int* __restrict__ tref_ptr,
                float* __restrict__ Sw, float* __restrict__ Swy, float* __restrict__ Swx,
                float* __restrict__ Fw, float* __restrict__ Fwy, float* __restrict__ Fwx) {
    __shared__ float sw[TCELLS], swy[TCELLS], swx[TCELLS];
    const int tid = threadIdx.x;
    for (int e = tid; e < TCELLS; e += 256) { sw[e] = 0.f; swy[e] = 0.f; swx[e] = 0.f; }
    __syncthreads();

    const int bx = blockIdx.x, by = blockIdx.y, b = blockIdx.z;
    const int tx0 = bx * TW, ty0 = by * TH;
    const int i = *i_ptr;
    const float dt = (float)(*tref_ptr - i);
    const float* __restrict__ fxp = fx_all + (size_t)(b * PP + i) * NN;
    const float* __restrict__ fyp = fy_all + (size_t)(b * PP + i) * NN;

    for (int sp = tid; sp < RGN; sp += 256) {
        int sy = sp / RGW, sx = sp - sy * RGW;
        int gy = ty0 - HALO + sy, gx = tx0 - HALO + sx;
        if ((unsigned)gy >= (unsigned)HH || (unsigned)gx >= (unsigned)WW) continue;
        int p = gy * WW + gx;
        float fx = fxp[p], fy = fyp[p];
        float wyf = (float)gy + dt * fy;
        float wxf = (float)gx + dt * fx;
        if (!(wyf >= 0.0f && wyf <= (float)(HH - 1) &&
              wxf >= 0.0f && wxf <= (float)(WW - 1))) continue;
        float tyf = floorf(wyf), lxf = floorf(wxf);
        float fry = wyf - tyf, frx = wxf - lxf;
        int iy0 = (int)tyf, ix0 = (int)lxf;
        bool interior = ((unsigned)(gx - tx0) < (unsigned)TW) &&
                        ((unsigned)(gy - ty0) < (unsigned)TH);
        float wts[4] = {(1.0f - fry) * (1.0f - frx),
                        (1.0f - fry) * frx,
                        fry * (1.0f - frx),
                        fry * frx};
#pragma unroll
        for (int k = 0; k < 4; ++k) {
            int iy = iy0 + (k >> 1), ix = ix0 + (k & 1);
            if ((unsigned)iy >= (unsigned)HH || (unsigned)ix >= (unsigned)WW) continue;
            float w = wts[k];
            int ly = iy - ty0, lx = ix - tx0;
            if ((unsigned)ly < (unsigned)TH && (unsigned)lx < (unsigned)TW) {
                int e = ly * TW + lx;
                atomic_add_f32(&sw[e],  w);
                atomic_add_f32(&swy[e], w * fy);
                atomic_add_f32(&swx[e], w * fx);
            } else if (interior) {
                // I own s. If N's tile does NOT cover s, nobody LDS-adds -> F.
                int tnx = (ix >> 6) << 6;   // tile(N) origin (TW=64)
                int tny = (iy >> 5) << 5;   // (TH=32)
                int ddx = gx < tnx ? tnx - gx : (gx > tnx + (TW - 1) ? gx - tnx - (TW - 1) : 0);
                int ddy = gy < tny ? tny - gy : (gy > tny + (TH - 1) ? gy - tny - (TH - 1) : 0);
                if (ddx > HALO || ddy > HALO) {
                    int fi = b * NN + iy * WW + ix;
                    atomic_add_f32(&Fw[fi],  w);
                    atomic_add_f32(&Fwy[fi], w * fy);
                    atomic_add_f32(&Fwx[fi], w * fx);
                }
            }
        }
    }
    __syncthreads();

    // Flush exact per-cell sums, plane-major, coalesced 64-float rows.
    size_t obase = (size_t)b * NN + (size_t)ty0 * WW + tx0;
    for (int e = tid; e < TCELLS; e += 256) {
        int r = e >> 6, c = e & 63;  // TW=64
        size_t o = obase + (size_t)r * WW + c;
        Sw[o] = sw[e]; Swy[o] = swy[e]; Swx[o] = swx[e];
    }
}

// ---------------- A/B twin: identical, but plain LDS writes (garbage out) ----
__global__ __launch_bounds__(256)
void splat_tile_w(const float* __restrict__ fx_all,
                  const float* __restrict__ fy_all,
                  const int* __restrict__ i_ptr,
                  const int* __restrict__ tref_ptr,
                  float* __restrict__ Sw, float* __restrict__ Swy, float* __restrict__ Swx,
                  float* __restrict__ Fw, float* __restrict__ Fwy, float* __restrict__ Fwx) {
    __shared__ float sw[TCELLS], swy[TCELLS], swx[TCELLS];
    const int tid = threadIdx.x;
    for (int e = tid; e < TCELLS; e += 256) { sw[e] = 0.f; swy[e] = 0.f; swx[e] = 0.f; }
    __syncthreads();

    const int bx = blockIdx.x, by = blockIdx.y, b = blockIdx.z;
    const int tx0 = bx * TW, ty0 = by * TH;
    const int i = *i_ptr;
    const float dt = (float)(*tref_ptr - i);
    const float* __restrict__ fxp = fx_all + (size_t)(b * PP + i) * NN;
    const float* __restrict__ fyp = fy_all + (size_t)(b * PP + i) * NN;

    for (int sp = tid; sp < RGN; sp += 256) {
        int sy = sp / RGW, sx = sp - sy * RGW;
        int gy = ty0 - HALO + sy, gx = tx0 - HALO + sx;
        if ((unsigned)gy >= (unsigned)HH || (unsigned)gx >= (unsigned)WW) continue;
        int p = gy * WW + gx;
        float fx = fxp[p], fy = fyp[p];
        float wyf = (float)gy + dt * fy;
        float wxf = (float)gx + dt * fx;
        if (!(wyf >= 0.0f && wyf <= (float)(HH - 1) &&
              wxf >= 0.0f && wxf <= (float)(WW - 1))) continue;
        float tyf = floorf(wyf), lxf = floorf(wxf);
        float fry = wyf - tyf, frx = wxf - lxf;
        int iy0 = (int)tyf, ix0 = (int)lxf;
        bool interior = ((unsigned)(gx - tx0) < (unsigned)TW) &&
                        ((unsigned)(gy - ty0) < (unsigned)TH);
        float wts[4] = {(1.0f - fry) * (1.0f - frx),
                        (1.0f - fry) * frx,
                        fry * (1.0f - frx),
                        fry * frx};
#pragma unroll
        for (int k = 0; k < 4; ++k) {
            int iy = iy0 + (k >> 1), ix = ix0 + (k & 1);
            if ((unsigned)iy >= (unsigned)HH || (unsigned)ix >= (unsigned)WW) continue;
            float w = wts[k];
            int ly = iy - ty0, lx = ix - tx0;
            if ((unsigned)ly < (unsigned)TH && (unsigned)lx < (unsigned)TW) {
                int e = ly * TW + lx;
                sw[e]  = w;            // plain write (wrong results; scratch only)
                swy[e] = w * fy;
                swx[e] = w * fx;
            } else if (interior) {
                int tnx = (ix >> 6) << 6;
                int tny = (iy >> 5) << 5;
                int ddx = gx < tnx ? tnx - gx : (gx > tnx + (TW - 1) ? gx - tnx - (TW - 1) : 0);
                int ddy = gy < tny ? tny - gy : (gy > tny + (TH - 1) ? gy - tny - (TH - 1) : 0);
                if (ddx > HALO || ddy > HALO) {
                    int fi = b * NN + iy * WW + ix;
                    atomic_add_f32(&Fw[fi],  w);   // runs pre-memset; cleared after
                    atomic_add_f32(&Fwy[fi], w * fy);
                    atomic_add_f32(&Fwx[fi], w * fx);
                }
            }
        }
    }
    __syncthreads();

    size_t obase = (size_t)b * NN + (size_t)ty0 * WW + tx0;
    for (int e = tid; e < TCELLS; e += 256) {
        int r = e >> 6, c = e & 63;
        size_t o = obase + (size_t)r * WW + c;
        Sw[o] = sw[e]; Swy[o] = swy[e]; Swx[o] = swx[e];
    }
}

// ---------------- merge + normalize ----------------
__global__ __launch_bounds__(256)
void merge_finalize(const float* __restrict__ Sw, const float* __restrict__ Swy,
                    const float* __restrict__ Swx,
                    const float* __restrict__ Fw, const float* __restrict__ Fwy,
                    const float* __restrict__ Fwx, float* __restrict__ out) {
    int t = blockIdx.x * blockDim.x + threadIdx.x;
    if (t >= BB * NN) return;
    float w  = Sw[t]  + Fw[t];
    float wy = Swy[t] + Fwy[t];
    float wx = Swx[t] + Fwx[t];
    float d = w + EPS;
    out[t]                   = wx / d;
    out[(size_t)BB * NN + t] = wy / d;
}

// ---------------- fallback path (R1, needs only 29.5 MB ws) ----------------

__global__ void splat_kernel(const float* __restrict__ fx_all,
                             const float* __restrict__ fy_all,
                             const int* __restrict__ i_ptr,
                             const int* __restrict__ tref_ptr,
                             float* __restrict__ sum_w,
                             float* __restrict__ sum_wy,
                             float* __restrict__ sum_wx) {
    int t = blockIdx.x * blockDim.x + threadIdx.x;
    if (t >= BB * NN) return;
    int b = t / NN;
    int p = t - b * NN;
    int i = *i_ptr;
    float dt = (float)(*tref_ptr - i);
    const float fx = fx_all[(size_t)(b * PP + i) * NN + p];
    const float fy = fy_all[(size_t)(b * PP + i) * NN + p];
    float gy = (float)(p / WW);
    float gx = (float)(p - (p / WW) * WW);
    float wy = gy + dt * fy;
    float wx = gx + dt * fx;
    bool inside = (wy >= 0.0f) && (wy <= (float)(HH - 1)) &&
                  (wx >= 0.0f) && (wx <= (float)(WW - 1));
    if (!inside) return;
    float ty = floorf(wy);
    float lx = floorf(wx);
    int base = b * NN;
#pragma unroll
    for (int k = 0; k < 4; ++k) {
        float ny = ty + (float)(k >> 1);
        float nx = lx + (float)(k & 1);
        int iy = (int)ny;
        int ix = (int)nx;
        if (iy < 0 || iy >= HH || ix < 0 || ix >= WW) continue;
        float wgt_y = fminf(fmaxf(1.0f - fabsf(wy - ny), 0.0f), 1.0f);
        float wgt_x = fminf(fmaxf(1.0f - fabsf(wx - nx), 0.0f), 1.0f);
        float w = wgt_y * wgt_x;
        int fi = base + iy * WW + ix;
        atomic_add_f32(&sum_w[fi],  w);
        atomic_add_f32(&sum_wy[fi], w * fy);
        atomic_add_f32(&sum_wx[fi], w * fx);
    }
}

__global__ void finalize_kernel(const float* __restrict__ sum_w,
                                const float* __restrict__ sum_wy,
                                const float* __restrict__ sum_wx,
                                float* __restrict__ out) {
    int t = blockIdx.x * blockDim.x + threadIdx.x;
    if (t >= BB * NN) return;
    float denom = sum_w[t] + EPS;
    out[t]                   = sum_wx[t] / denom;
    out[(size_t)BB * NN + t] = sum_wy[t] / denom;
}

// ---------------- launch ----------------

extern "C" void kernel_launch(void* const* d_in, const int* in_sizes, int n_in,
                              void* d_out, int out_size, void* d_ws, size_t ws_size,
                              hipStream_t stream) {
    const float* fx_all = (const float*)d_in[0];
    const float* fy_all = (const float*)d_in[1];
    const int* i_ptr    = (const int*)d_in[2];
    const int* tref_ptr = (const int*)d_in[3];
    float* out = (float*)d_out;

    const size_t BN = (size_t)BB * NN;           // 2.4576 M cells
    // ws layout: Sw|Swy|Swx|Fw|Fwy|Fwx|S2(3 planes for twin) = 9 planes
    if (ws_size >= 9 * BN * sizeof(float)) {
        float* Sw  = (float*)d_ws;
        float* Swy = Sw  + BN;
        float* Swx = Swy + BN;
        float* Fw  = Swx + BN;
        float* Fwy = Fw  + BN;
        float* Fwx = Fwy + BN;
        float* S2  = Fwx + BN;   // twin scratch (3 planes)

        dim3 grid(NBX, NBY, BB);

        // A/B twin first (garbage into S2; its F-atomics are cleared below)
        splat_tile_w<<<grid, 256, 0, stream>>>(fx_all, fy_all, i_ptr, tref_ptr,
                                               S2, S2 + BN, S2 + 2 * BN, Fw, Fwy, Fwx);
        // Zero fallback planes, then the real pipeline
        hipMemsetAsync(Fw, 0, 3 * BN * sizeof(float), stream);
        splat_tile<<<grid, 256, 0, stream>>>(fx_all, fy_all, i_ptr, tref_ptr,
                                             Sw, Swy, Swx, Fw, Fwy, Fwx);
        int total = (int)BN;
        merge_finalize<<<(total + 255) / 256, 256, 0, stream>>>(Sw, Swy, Swx,
                                                                Fw, Fwy, Fwx, out);
    } else {
        // R1 fallback: plain global-atomic splat
        float* sum_w  = (float*)d_ws;
        float* sum_wy = sum_w + BN;
        float* sum_wx = sum_wy + BN;
        hipMemsetAsync(d_ws, 0, 3 * BN * sizeof(float), stream);
        int total = (int)BN;
        int block = 256;
        int grid1 = (total + block - 1) / block;
        splat_kernel<<<grid1, block, 0, stream>>>(fx_all, fy_all, i_ptr, tref_ptr,
                                                  sum_w, sum_wy, sum_wx);
        finalize_kernel<<<grid1, block, 0, stream>>>(sum_w, sum_wy, sum_wx, out);
    }
}

// Round 6
// 190.029 us; speedup vs baseline: 2.4591x; 1.1322x over previous
//
#include <hip/hip_runtime.h>
#include <stdint.h>

// Problem constants (fixed by the reference's config)
#define HH 480
#define WW 640
#define NN (HH * WW)
#define BB 8
#define PP 4
#define EPS 1e-9f

// Output-tile geometry: each block owns a TW x TH OUTPUT tile and reads the
// source halo region around it. Image exactly tiled: 640/64=10, 480/32=15.
#define TW 64
#define TH 32
#define HALO 12
#define RGW (TW + 2 * HALO)   // 88
#define RGH (TH + 2 * HALO)   // 56
#define RGN (RGW * RGH)       // 4928
#define TCELLS (TW * TH)      // 2048
#define NBX (WW / TW)         // 10
#define NBY (HH / TH)         // 15

// Native LDS f32 atomic add, fire-and-forget. Plain atomicAdd/unsafeAtomicAdd
// on LDS f32 lowers to a CAS retry loop under IEEE denormal mode (R2-R5:
// ~250 cy/op serialized; plain-write twin was 5.5x faster). ds_add_f32
// flushes denorms -- harmless here (|values| >= ~1e-7).
__device__ __forceinline__ void lds_add_f32(float* p, float v) {
    asm volatile("ds_add_f32 %0, %1"
                 :: "v"((uint32_t)(uintptr_t)p), "v"(v)
                 : "memory");
}

__device__ __forceinline__ void atomic_add_f32_global(float* p, float v) {
    unsafeAtomicAdd(p, v);  // rare path (~6K ops total)
}

// ---------------- main splat: output-tile centric ----------------
// Block (tile T) processes all sources s with dist_inf(s,T) <= HALO.
// Neighbor N of s: if N in T -> LDS add. Else, if s interior to T and N's
// own tile does not cover s (dist > HALO), T adds to global F exactly once.
__global__ __launch_bounds__(256)
void splat_tile(const float* __restrict__ fx_all,
                const float* __restrict__ fy_all,
                const int* __restrict__ i_ptr,
                const int* __restrict__ tref_ptr,
                float* __restrict__ Sw, float* __restrict__ Swy, float* __restrict__ Swx,
                float* __restrict__ Fw, float* __restrict__ Fwy, float* __restrict__ Fwx) {
    // interleaved planes: cell e -> sacc[3e+0]=w, [3e+1]=w*fy, [3e+2]=w*fx
    // (stride 3 is coprime with 32 banks -> the per-neighbor triple hits 3
    //  consecutive banks, and stride-3 flush reads are conflict-free)
    __shared__ float sacc[TCELLS * 3];
    const int tid = threadIdx.x;
    for (int e = tid; e < TCELLS * 3; e += 256) sacc[e] = 0.0f;
    __syncthreads();

    const int bx = blockIdx.x, by = blockIdx.y, b = blockIdx.z;
    const int tx0 = bx * TW, ty0 = by * TH;
    const int i = *i_ptr;
    const float dt = (float)(*tref_ptr - i);
    const float* __restrict__ fxp = fx_all + (size_t)(b * PP + i) * NN;
    const float* __restrict__ fyp = fy_all + (size_t)(b * PP + i) * NN;

    for (int sp = tid; sp < RGN; sp += 256) {
        int sy = sp / RGW, sx = sp - sy * RGW;
        int gy = ty0 - HALO + sy, gx = tx0 - HALO + sx;
        if ((unsigned)gy >= (unsigned)HH || (unsigned)gx >= (unsigned)WW) continue;
        int p = gy * WW + gx;
        float fx = fxp[p], fy = fyp[p];
        float wyf = (float)gy + dt * fy;
        float wxf = (float)gx + dt * fx;
        if (!(wyf >= 0.0f && wyf <= (float)(HH - 1) &&
              wxf >= 0.0f && wxf <= (float)(WW - 1))) continue;
        float tyf = floorf(wyf), lxf = floorf(wxf);
        float fry = wyf - tyf, frx = wxf - lxf;
        int iy0 = (int)tyf, ix0 = (int)lxf;
        bool interior = ((unsigned)(gx - tx0) < (unsigned)TW) &&
                        ((unsigned)(gy - ty0) < (unsigned)TH);
        float wts[4] = {(1.0f - fry) * (1.0f - frx),
                        (1.0f - fry) * frx,
                        fry * (1.0f - frx),
                        fry * frx};
#pragma unroll
        for (int k = 0; k < 4; ++k) {
            int iy = iy0 + (k >> 1), ix = ix0 + (k & 1);
            if ((unsigned)iy >= (unsigned)HH || (unsigned)ix >= (unsigned)WW) continue;
            float w = wts[k];
            int ly = iy - ty0, lx = ix - tx0;
            if ((unsigned)ly < (unsigned)TH && (unsigned)lx < (unsigned)TW) {
                float* cell = &sacc[(ly * TW + lx) * 3];
                lds_add_f32(cell + 0, w);
                lds_add_f32(cell + 1, w * fy);
                lds_add_f32(cell + 2, w * fx);
            } else if (interior) {
                int tnx = (ix >> 6) << 6;   // tile(N) origin (TW=64)
                int tny = (iy >> 5) << 5;   // (TH=32)
                int ddx = gx < tnx ? tnx - gx : (gx > tnx + (TW - 1) ? gx - tnx - (TW - 1) : 0);
                int ddy = gy < tny ? tny - gy : (gy > tny + (TH - 1) ? gy - tny - (TH - 1) : 0);
                if (ddx > HALO || ddy > HALO) {
                    int fi = b * NN + iy * WW + ix;
                    atomic_add_f32_global(&Fw[fi],  w);
                    atomic_add_f32_global(&Fwy[fi], w * fy);
                    atomic_add_f32_global(&Fwx[fi], w * fx);
                }
            }
        }
    }
    // Drain our asm DS ops before the barrier (compiler can't track them).
    asm volatile("s_waitcnt lgkmcnt(0)" ::: "memory");
    __syncthreads();

    // Flush exact per-cell sums, plane-major, coalesced rows.
    size_t obase = (size_t)b * NN + (size_t)ty0 * WW + tx0;
    for (int e = tid; e < TCELLS; e += 256) {
        int r = e >> 6, c = e & 63;  // TW=64
        size_t o = obase + (size_t)r * WW + c;
        Sw[o]  = sacc[e * 3 + 0];
        Swy[o] = sacc[e * 3 + 1];
        Swx[o] = sacc[e * 3 + 2];
    }
}

// ---------------- merge + normalize ----------------
__global__ __launch_bounds__(256)
void merge_finalize(const float* __restrict__ Sw, const float* __restrict__ Swy,
                    const float* __restrict__ Swx,
                    const float* __restrict__ Fw, const float* __restrict__ Fwy,
                    const float* __restrict__ Fwx, float* __restrict__ out) {
    int t = blockIdx.x * blockDim.x + threadIdx.x;
    if (t >= BB * NN) return;
    float w  = Sw[t]  + Fw[t];
    float wy = Swy[t] + Fwy[t];
    float wx = Swx[t] + Fwx[t];
    float d = w + EPS;
    out[t]                   = wx / d;
    out[(size_t)BB * NN + t] = wy / d;
}

// ---------------- fallback path (R1, needs only 29.5 MB ws) ----------------

__global__ void splat_kernel(const float* __restrict__ fx_all,
                             const float* __restrict__ fy_all,
                             const int* __restrict__ i_ptr,
                             const int* __restrict__ tref_ptr,
                             float* __restrict__ sum_w,
                             float* __restrict__ sum_wy,
                             float* __restrict__ sum_wx) {
    int t = blockIdx.x * blockDim.x + threadIdx.x;
    if (t >= BB * NN) return;
    int b = t / NN;
    int p = t - b * NN;
    int i = *i_ptr;
    float dt = (float)(*tref_ptr - i);
    const float fx = fx_all[(size_t)(b * PP + i) * NN + p];
    const float fy = fy_all[(size_t)(b * PP + i) * NN + p];
    float gy = (float)(p / WW);
    float gx = (float)(p - (p / WW) * WW);
    float wy = gy + dt * fy;
    float wx = gx + dt * fx;
    bool inside = (wy >= 0.0f) && (wy <= (float)(HH - 1)) &&
                  (wx >= 0.0f) && (wx <= (float)(WW - 1));
    if (!inside) return;
    float ty = floorf(wy);
    float lx = floorf(wx);
    int base = b * NN;
#pragma unroll
    for (int k = 0; k < 4; ++k) {
        float ny = ty + (float)(k >> 1);
        float nx = lx + (float)(k & 1);
        int iy = (int)ny;
        int ix = (int)nx;
        if (iy < 0 || iy >= HH || ix < 0 || ix >= WW) continue;
        float wgt_y = fminf(fmaxf(1.0f - fabsf(wy - ny), 0.0f), 1.0f);
        float wgt_x = fminf(fmaxf(1.0f - fabsf(wx - nx), 0.0f), 1.0f);
        float w = wgt_y * wgt_x;
        int fi = base + iy * WW + ix;
        atomic_add_f32_global(&sum_w[fi],  w);
        atomic_add_f32_global(&sum_wy[fi], w * fy);
        atomic_add_f32_global(&sum_wx[fi], w * fx);
    }
}

__global__ void finalize_kernel(const float* __restrict__ sum_w,
                                const float* __restrict__ sum_wy,
                                const float* __restrict__ sum_wx,
                                float* __restrict__ out) {
    int t = blockIdx.x * blockDim.x + threadIdx.x;
    if (t >= BB * NN) return;
    float denom = sum_w[t] + EPS;
    out[t]                   = sum_wx[t] / denom;
    out[(size_t)BB * NN + t] = sum_wy[t] / denom;
}

// ---------------- launch ----------------

extern "C" void kernel_launch(void* const* d_in, const int* in_sizes, int n_in,
                              void* d_out, int out_size, void* d_ws, size_t ws_size,
                              hipStream_t stream) {
    const float* fx_all = (const float*)d_in[0];
    const float* fy_all = (const float*)d_in[1];
    const int* i_ptr    = (const int*)d_in[2];
    const int* tref_ptr = (const int*)d_in[3];
    float* out = (float*)d_out;

    const size_t BN = (size_t)BB * NN;   // 2.4576 M cells
    // ws layout: Sw|Swy|Swx|Fw|Fwy|Fwx = 6 planes
    if (ws_size >= 6 * BN * sizeof(float)) {
        float* Sw  = (float*)d_ws;
        float* Swy = Sw  + BN;
        float* Swx = Swy + BN;
        float* Fw  = Swx + BN;
        float* Fwy = Fw  + BN;
        float* Fwx = Fwy + BN;

        hipMemsetAsync(Fw, 0, 3 * BN * sizeof(float), stream);
        dim3 grid(NBX, NBY, BB);
        splat_tile<<<grid, 256, 0, stream>>>(fx_all, fy_all, i_ptr, tref_ptr,
                                             Sw, Swy, Swx, Fw, Fwy, Fwx);
        int total = (int)BN;
        merge_finalize<<<(total + 255) / 256, 256, 0, stream>>>(Sw, Swy, Swx,
                                                                Fw, Fwy, Fwx, out);
    } else {
        // R1 fallback: plain global-atomic splat
        float* sum_w  = (float*)d_ws;
        float* sum_wy = sum_w + BN;
        float* sum_wx = sum_wy + BN;
        hipMemsetAsync(d_ws, 0, 3 * BN * sizeof(float), stream);
        int total = (int)BN;
        int block = 256;
        int grid1 = (total + block - 1) / block;
        splat_kernel<<<grid1, block, 0, stream>>>(fx_all, fy_all, i_ptr, tref_ptr,
                                                  sum_w, sum_wy, sum_wx);
        finalize_kernel<<<grid1, block, 0, stream>>>(sum_w, sum_wy, sum_wx, out);
    }
}

// Round 7
// 134.729 us; speedup vs baseline: 3.4685x; 1.4105x over previous
//
#include <hip/hip_runtime.h>
#include <stdint.h>

// Problem constants (fixed by the reference's config)
#define HH 480
#define WW 640
#define NN (HH * WW)
#define BB 8
#define PP 4
#define EPS 1e-9f

// Output-tile geometry: block owns a TW x TH OUTPUT tile. 640/64=10, 480/32=15.
#define TW 64
#define TH 32
#define HALO 12
#define RGW (TW + 2 * HALO)   // 88  source region width
#define RGH (TH + 2 * HALO)   // 56  source region height
#define RGN (RGW * RGH)       // 4928
#define NBX (WW / TW)         // 10
#define NBY (HH / TH)         // 15

// Binning: sources bucketed by floor cell; floors relevant to this tile are
// rel rows [-1, TH-1], cols [-1, TW-1].
#define BINSX (TW + 1)        // 65
#define BINSY (TH + 1)        // 33
#define NBINS (BINSX * BINSY) // 2145
#define CAP 4                 // slots/bin; Poisson(1) P(>4) ~ 0.4% -> F path

__device__ __forceinline__ void gatomic(float* p, float v) {
    unsafeAtomicAdd(p, v);    // native global_atomic_add_f32, rare path only
}

// One kernel, two phases:
//  A) scan source halo region, stage flow in LDS, bin sources by floor cell
//     (1 int rtn-atomic per source instead of 12 float atomics),
//     far/overflow contributions -> global F (exactly-once ownership rules).
//  B) each output cell gathers from its 4 adjacent bins, recomputes exact
//     f32 weights, accumulates in registers, coalesced plain stores.
__global__ __launch_bounds__(256)
void bin_gather_splat(const float* __restrict__ fx_all,
                      const float* __restrict__ fy_all,
                      const int* __restrict__ i_ptr,
                      const int* __restrict__ tref_ptr,
                      float* __restrict__ Sw, float* __restrict__ Swy, float* __restrict__ Swx,
                      float* __restrict__ Fw, float* __restrict__ Fwy, float* __restrict__ Fwx) {
    __shared__ unsigned cnt[NBINS];              // 8580 B
    __shared__ unsigned short ids[NBINS * CAP];  // 17160 B
    __shared__ float sflow[RGN * 2];             // 39424 B  (fy,fx) per source
    const int tid = threadIdx.x;
    for (int e = tid; e < NBINS; e += 256) cnt[e] = 0;
    __syncthreads();

    const int bx = blockIdx.x, by = blockIdx.y, b = blockIdx.z;
    const int tx0 = bx * TW, ty0 = by * TH;
    const int i = *i_ptr;
    const float dt = (float)(*tref_ptr - i);
    const float* __restrict__ fxp = fx_all + (size_t)(b * PP + i) * NN;
    const float* __restrict__ fyp = fy_all + (size_t)(b * PP + i) * NN;

    // ---------------- phase A ----------------
    for (int sp = tid; sp < RGN; sp += 256) {
        int sy = sp / RGW, sx = sp - sy * RGW;
        int gy = ty0 - HALO + sy, gx = tx0 - HALO + sx;
        if ((unsigned)gy >= (unsigned)HH || (unsigned)gx >= (unsigned)WW) continue;
        int p = gy * WW + gx;
        float fx = fxp[p], fy = fyp[p];
        sflow[sp * 2 + 0] = fy;
        sflow[sp * 2 + 1] = fx;
        float wyf = (float)gy + dt * fy;
        float wxf = (float)gx + dt * fx;
        // purge_unfeasible
        if (!(wyf >= 0.0f && wyf <= (float)(HH - 1) &&
              wxf >= 0.0f && wxf <= (float)(WW - 1))) continue;
        float tyf = floorf(wyf), lxf = floorf(wxf);
        int iy0 = (int)tyf, ix0 = (int)lxf;   // >= 0 (inside test)
        int br = iy0 - ty0, bc = ix0 - tx0;

        bool overflow = false;
        if (br >= -1 && br < TH && bc >= -1 && bc < TW) {
            int bin = (br + 1) * BINSX + (bc + 1);
            unsigned slot = atomicAdd(&cnt[bin], 1u);   // native ds_add_rtn_u32
            if (slot < CAP) ids[bin * CAP + slot] = (unsigned short)((sy << 7) | sx);
            else overflow = true;
        }
        bool interior = ((unsigned)(gx - tx0) < (unsigned)TW) &&
                        ((unsigned)(gy - ty0) < (unsigned)TH);
        if (overflow || interior) {
            float fry = wyf - tyf, frx = wxf - lxf;
            float wts[4] = {(1.0f - fry) * (1.0f - frx),
                            (1.0f - fry) * frx,
                            fry * (1.0f - frx),
                            fry * frx};
#pragma unroll
            for (int k = 0; k < 4; ++k) {
                int iy = iy0 + (k >> 1), ix = ix0 + (k & 1);
                if ((unsigned)iy >= (unsigned)HH || (unsigned)ix >= (unsigned)WW) continue;
                bool inT = ((unsigned)(iy - ty0) < (unsigned)TH) &&
                           ((unsigned)(ix - tx0) < (unsigned)TW);
                // far: s's owner must emit (N's tile never scans s)
                int tnx = (ix >> 6) << 6;   // tile(N) origin, TW=64
                int tny = (iy >> 5) << 5;   // TH=32
                int ddx = gx < tnx ? tnx - gx : (gx > tnx + (TW - 1) ? gx - tnx - (TW - 1) : 0);
                int ddy = gy < tny ? tny - gy : (gy > tny + (TH - 1) ? gy - tny - (TH - 1) : 0);
                bool far = (ddx > HALO) || (ddy > HALO);
                if ((interior && far) || (overflow && inT)) {
                    int fi = b * NN + iy * WW + ix;
                    float w = wts[k];
                    gatomic(&Fw[fi],  w);
                    gatomic(&Fwy[fi], w * fy);
                    gatomic(&Fwx[fi], w * fx);
                }
            }
        }
    }
    __syncthreads();

    // ---------------- phase B: gather ----------------
    for (int e = tid; e < TW * TH; e += 256) {
        int r = e >> 6, c = e & 63;           // TW=64
        float cy = (float)(ty0 + r), cx = (float)(tx0 + c);
        float ws = 0.f, wys = 0.f, wxs = 0.f;
#pragma unroll
        for (int dr = 0; dr < 2; ++dr) {
#pragma unroll
            for (int dc = 0; dc < 2; ++dc) {
                int bin = (r + dr) * BINSX + (c + dc);  // (r-1+dr)+1, (c-1+dc)+1
                unsigned n = cnt[bin];
                if (n > CAP) n = CAP;
                for (unsigned t = 0; t < n; ++t) {
                    int id = ids[bin * CAP + t];
                    int sy = id >> 7, sx = id & 127;
                    int gy = ty0 - HALO + sy, gx = tx0 - HALO + sx;
                    int sp = sy * RGW + sx;
                    float fy = sflow[sp * 2 + 0];
                    float fx = sflow[sp * 2 + 1];
                    float wyf = (float)gy + dt * fy;   // exact same f32 ops as phase A
                    float wxf = (float)gx + dt * fx;
                    float ay = 1.0f - fabsf(wyf - cy);
                    float ax = 1.0f - fabsf(wxf - cx);
                    float w = fmaxf(ay, 0.0f) * fmaxf(ax, 0.0f);
                    ws  += w;
                    wys += w * fy;
                    wxs += w * fx;
                }
            }
        }
        size_t o = (size_t)b * NN + (size_t)(ty0 + r) * WW + (tx0 + c);
        Sw[o] = ws; Swy[o] = wys; Swx[o] = wxs;
    }
}

// ---------------- merge + normalize ----------------
__global__ __launch_bounds__(256)
void merge_finalize(const float* __restrict__ Sw, const float* __restrict__ Swy,
                    const float* __restrict__ Swx,
                    const float* __restrict__ Fw, const float* __restrict__ Fwy,
                    const float* __restrict__ Fwx, float* __restrict__ out) {
    int t = blockIdx.x * blockDim.x + threadIdx.x;
    if (t >= BB * NN) return;
    float w  = Sw[t]  + Fw[t];
    float wy = Swy[t] + Fwy[t];
    float wx = Swx[t] + Fwx[t];
    float d = w + EPS;
    out[t]                   = wx / d;
    out[(size_t)BB * NN + t] = wy / d;
}

// ---------------- fallback path (R1, needs only 29.5 MB ws) ----------------

__global__ void splat_kernel(const float* __restrict__ fx_all,
                             const float* __restrict__ fy_all,
                             const int* __restrict__ i_ptr,
                             const int* __restrict__ tref_ptr,
                             float* __restrict__ sum_w,
                             float* __restrict__ sum_wy,
                             float* __restrict__ sum_wx) {
    int t = blockIdx.x * blockDim.x + threadIdx.x;
    if (t >= BB * NN) return;
    int b = t / NN;
    int p = t - b * NN;
    int i = *i_ptr;
    float dt = (float)(*tref_ptr - i);
    const float fx = fx_all[(size_t)(b * PP + i) * NN + p];
    const float fy = fy_all[(size_t)(b * PP + i) * NN + p];
    float gy = (float)(p / WW);
    float gx = (float)(p - (p / WW) * WW);
    float wy = gy + dt * fy;
    float wx = gx + dt * fx;
    bool inside = (wy >= 0.0f) && (wy <= (float)(HH - 1)) &&
                  (wx >= 0.0f) && (wx <= (float)(WW - 1));
    if (!inside) return;
    float ty = floorf(wy);
    float lx = floorf(wx);
    int base = b * NN;
#pragma unroll
    for (int k = 0; k < 4; ++k) {
        float ny = ty + (float)(k >> 1);
        float nx = lx + (float)(k & 1);
        int iy = (int)ny;
        int ix = (int)nx;
        if (iy < 0 || iy >= HH || ix < 0 || ix >= WW) continue;
        float wgt_y = fminf(fmaxf(1.0f - fabsf(wy - ny), 0.0f), 1.0f);
        float wgt_x = fminf(fmaxf(1.0f - fabsf(wx - nx), 0.0f), 1.0f);
        float w = wgt_y * wgt_x;
        int fi = base + iy * WW + ix;
        gatomic(&sum_w[fi],  w);
        gatomic(&sum_wy[fi], w * fy);
        gatomic(&sum_wx[fi], w * fx);
    }
}

__global__ void finalize_kernel(const float* __restrict__ sum_w,
                                const float* __restrict__ sum_wy,
                                const float* __restrict__ sum_wx,
                                float* __restrict__ out) {
    int t = blockIdx.x * blockDim.x + threadIdx.x;
    if (t >= BB * NN) return;
    float denom = sum_w[t] + EPS;
    out[t]                   = sum_wx[t] / denom;
    out[(size_t)BB * NN + t] = sum_wy[t] / denom;
}

// ---------------- launch ----------------

extern "C" void kernel_launch(void* const* d_in, const int* in_sizes, int n_in,
                              void* d_out, int out_size, void* d_ws, size_t ws_size,
                              hipStream_t stream) {
    const float* fx_all = (const float*)d_in[0];
    const float* fy_all = (const float*)d_in[1];
    const int* i_ptr    = (const int*)d_in[2];
    const int* tref_ptr = (const int*)d_in[3];
    float* out = (float*)d_out;

    const size_t BN = (size_t)BB * NN;   // 2.4576 M cells
    // ws layout: Sw|Swy|Swx|Fw|Fwy|Fwx = 6 planes
    if (ws_size >= 6 * BN * sizeof(float)) {
        float* Sw  = (float*)d_ws;
        float* Swy = Sw  + BN;
        float* Swx = Swy + BN;
        float* Fw  = Swx + BN;
        float* Fwy = Fw  + BN;
        float* Fwx = Fwy + BN;

        hipMemsetAsync(Fw, 0, 3 * BN * sizeof(float), stream);
        dim3 grid(NBX, NBY, BB);
        bin_gather_splat<<<grid, 256, 0, stream>>>(fx_all, fy_all, i_ptr, tref_ptr,
                                                   Sw, Swy, Swx, Fw, Fwy, Fwx);
        int total = (int)BN;
        merge_finalize<<<(total + 255) / 256, 256, 0, stream>>>(Sw, Swy, Swx,
                                                                Fw, Fwy, Fwx, out);
    } else {
        // R1 fallback: global-atomic splat (native adds)
        float* sum_w  = (float*)d_ws;
        float* sum_wy = sum_w + BN;
        float* sum_wx = sum_wy + BN;
        hipMemsetAsync(d_ws, 0, 3 * BN * sizeof(float), stream);
        int total = (int)BN;
        int block = 256;
        int grid1 = (total + block - 1) / block;
        splat_kernel<<<grid1, block, 0, stream>>>(fx_all, fy_all, i_ptr, tref_ptr,
                                                  sum_w, sum_wy, sum_wx);
        finalize_kernel<<<grid1, block, 0, stream>>>(sum_w, sum_wy, sum_wx, out);
    }
}

// Round 9
// 103.074 us; speedup vs baseline: 4.5337x; 1.3071x over previous
//
#include <hip/hip_runtime.h>
#include <stdint.h>

// Problem constants (fixed by the reference's config)
#define HH 480
#define WW 640
#define NN (HH * WW)
#define BB 8
#define PP 4
#define EPS 1e-9f

// Output-tile geometry: block owns a TW x TH OUTPUT tile. 640/64=10, 480/32=15.
#define TW 64
#define TH 32
#define HALO 12
#define RGW (TW + 2 * HALO)   // 88  source region width
#define RGH (TH + 2 * HALO)   // 56  source region height
#define RGN (RGW * RGH)       // 4928
#define NBX (WW / TW)         // 10
#define NBY (HH / TH)         // 15

// Binning: sources bucketed by floor cell; floors relevant to this tile are
// rel rows [-1, TH-1], cols [-1, TW-1].
#define BINSX (TW + 1)        // 65
#define BINSY (TH + 1)        // 33
#define NBINS (BINSX * BINSY) // 2145
#define CAP 4                 // slots/bin; Poisson(1) P(>4) ~ 0.4% -> F path

// id of a guaranteed-in-image source (rel HALO,HALO == tile origin), used for
// invalid slots so their (dead, weight-0) global loads are in-bounds.
#define SAFE_ID ((HALO << 7) | HALO)

__device__ __forceinline__ void gatomic(float* p, float v) {
    unsafeAtomicAdd(p, v);    // native global_atomic_add_f32, rare path only
}

// Phases: A) scan halo region, bin sources by floor cell (1 int rtn-atomic
// per source); far/overflow -> global F exactly once. B) per output cell:
// 4 adjacent bins x 4 predicated slots; flow re-read from global (L1-hot,
// bit-identical to phase A inputs -> identical f32 warp/weights), register
// accumulate, coalesced stores. LDS 25.7 KB; VGPR<=128 -> 4 blocks/CU.
__global__ __launch_bounds__(256, 4)
void bin_gather_splat(const float* __restrict__ fx_all,
                      const float* __restrict__ fy_all,
                      const int* __restrict__ i_ptr,
                      const int* __restrict__ tref_ptr,
                      float* __restrict__ Sw, float* __restrict__ Swy, float* __restrict__ Swx,
                      float* __restrict__ Fw, float* __restrict__ Fwy, float* __restrict__ Fwx) {
    __shared__ unsigned cnt[NBINS];   // 8580 B
    __shared__ ushort4  ids4[NBINS];  // 4 slots/bin, 8B-aligned, 17160 B
    const int tid = threadIdx.x;
    for (int e = tid; e < NBINS; e += 256) cnt[e] = 0;
    __syncthreads();

    const int bx = blockIdx.x, by = blockIdx.y, b = blockIdx.z;
    const int tx0 = bx * TW, ty0 = by * TH;
    const int i = *i_ptr;
    const float dt = (float)(*tref_ptr - i);
    const float* __restrict__ fxp = fx_all + (size_t)(b * PP + i) * NN;
    const float* __restrict__ fyp = fy_all + (size_t)(b * PP + i) * NN;

    // ---------------- phase A ----------------
    for (int sp = tid; sp < RGN; sp += 256) {
        int sy = sp / RGW, sx = sp - sy * RGW;
        int gy = ty0 - HALO + sy, gx = tx0 - HALO + sx;
        if ((unsigned)gy >= (unsigned)HH || (unsigned)gx >= (unsigned)WW) continue;
        int p = gy * WW + gx;
        float fy = fyp[p], fx = fxp[p];
        float wyf = (float)gy + dt * fy;
        float wxf = (float)gx + dt * fx;
        // purge_unfeasible
        if (!(wyf >= 0.0f && wyf <= (float)(HH - 1) &&
              wxf >= 0.0f && wxf <= (float)(WW - 1))) continue;
        float tyf = floorf(wyf), lxf = floorf(wxf);
        int iy0 = (int)tyf, ix0 = (int)lxf;   // >= 0 (inside test)
        int br = iy0 - ty0, bc = ix0 - tx0;

        bool overflow = false;
        if (br >= -1 && br < TH && bc >= -1 && bc < TW) {
            int bin = (br + 1) * BINSX + (bc + 1);
            unsigned slot = atomicAdd(&cnt[bin], 1u);   // native ds_add_rtn_u32
            if (slot < CAP)
                ((unsigned short*)&ids4[bin])[slot] = (unsigned short)((sy << 7) | sx);
            else overflow = true;
        }
        bool interior = ((unsigned)(gx - tx0) < (unsigned)TW) &&
                        ((unsigned)(gy - ty0) < (unsigned)TH);
        if (overflow || interior) {
            float fry = wyf - tyf, frx = wxf - lxf;
            float wts[4] = {(1.0f - fry) * (1.0f - frx),
                            (1.0f - fry) * frx,
                            fry * (1.0f - frx),
                            fry * frx};
#pragma unroll
            for (int k = 0; k < 4; ++k) {
                int iy = iy0 + (k >> 1), ix = ix0 + (k & 1);
                if ((unsigned)iy >= (unsigned)HH || (unsigned)ix >= (unsigned)WW) continue;
                bool inT = ((unsigned)(iy - ty0) < (unsigned)TH) &&
                           ((unsigned)(ix - tx0) < (unsigned)TW);
                // far: s's owner must emit (tile(N) never scans s)
                int tnx = (ix >> 6) << 6;   // tile(N) origin, TW=64
                int tny = (iy >> 5) << 5;   // TH=32
                int ddx = gx < tnx ? tnx - gx : (gx > tnx + (TW - 1) ? gx - tnx - (TW - 1) : 0);
                int ddy = gy < tny ? tny - gy : (gy > tny + (TH - 1) ? gy - tny - (TH - 1) : 0);
                bool far = (ddx > HALO) || (ddy > HALO);
                if ((interior && far) || (overflow && inT)) {
                    int fi = b * NN + iy * WW + ix;
                    float w = wts[k];
                    gatomic(&Fw[fi],  w);
                    gatomic(&Fwy[fi], w * fy);
                    gatomic(&Fwx[fi], w * fx);
                }
            }
        }
    }
    __syncthreads();

    // ---------------- phase B: fixed-trip predicated gather ----------------
    for (int e = tid; e < TW * TH; e += 256) {
        int r = e >> 6, c = e & 63;           // TW=64
        float cy = (float)(ty0 + r), cx = (float)(tx0 + c);
        float ws = 0.f, wys = 0.f, wxs = 0.f;
#pragma unroll
        for (int dr = 0; dr < 2; ++dr) {
#pragma unroll
            for (int dc = 0; dc < 2; ++dc) {
                int bin = (r + dr) * BINSX + (c + dc);
                unsigned n = cnt[bin];
                if (n > CAP) n = CAP;
                ushort4 s4 = ids4[bin];       // one ds_read_b64
                unsigned short sl[4] = {s4.x, s4.y, s4.z, s4.w};
#pragma unroll
                for (int t = 0; t < CAP; ++t) {
                    bool valid = (unsigned)t < n;
                    int id = valid ? (int)sl[t] : SAFE_ID;
                    int sy = id >> 7, sx = id & 127;
                    int gy = ty0 - HALO + sy, gx = tx0 - HALO + sx;
                    int p = gy * WW + gx;     // in-image by construction
                    float fy = fyp[p], fx = fxp[p];   // L1-hot, bit-identical
                    float wyf = (float)gy + dt * fy;  // same expr as phase A
                    float wxf = (float)gx + dt * fx;
                    float ay = 1.0f - fabsf(wyf - cy);
                    float ax = 1.0f - fabsf(wxf - cx);
                    float w = fmaxf(ay, 0.f) * fmaxf(ax, 0.f);
                    w = valid ? w : 0.f;
                    ws  += w;
                    wys += w * fy;
                    wxs += w * fx;
                }
            }
        }
        size_t o = (size_t)b * NN + (size_t)(ty0 + r) * WW + (tx0 + c);
        Sw[o] = ws; Swy[o] = wys; Swx[o] = wxs;
    }
}

// ---------------- merge + normalize ----------------
__global__ __launch_bounds__(256)
void merge_finalize(const float* __restrict__ Sw, const float* __restrict__ Swy,
                    const float* __restrict__ Swx,
                    const float* __restrict__ Fw, const float* __restrict__ Fwy,
                    const float* __restrict__ Fwx, float* __restrict__ out) {
    int t = blockIdx.x * blockDim.x + threadIdx.x;
    if (t >= BB * NN) return;
    float w  = Sw[t]  + Fw[t];
    float wy = Swy[t] + Fwy[t];
    float wx = Swx[t] + Fwx[t];
    float d = w + EPS;
    out[t]                   = wx / d;
    out[(size_t)BB * NN + t] = wy / d;
}

// ---------------- fallback path (R1, needs only 29.5 MB ws) ----------------

__global__ void splat_kernel(const float* __restrict__ fx_all,
                             const float* __restrict__ fy_all,
                             const int* __restrict__ i_ptr,
                             const int* __restrict__ tref_ptr,
                             float* __restrict__ sum_w,
                             float* __restrict__ sum_wy,
                             float* __restrict__ sum_wx) {
    int t = blockIdx.x * blockDim.x + threadIdx.x;
    if (t >= BB * NN) return;
    int b = t / NN;
    int p = t - b * NN;
    int i = *i_ptr;
    float dt = (float)(*tref_ptr - i);
    const float fx = fx_all[(size_t)(b * PP + i) * NN + p];
    const float fy = fy_all[(size_t)(b * PP + i) * NN + p];
    float gy = (float)(p / WW);
    float gx = (float)(p - (p / WW) * WW);
    float wy = gy + dt * fy;
    float wx = gx + dt * fx;
    bool inside = (wy >= 0.0f) && (wy <= (float)(HH - 1)) &&
                  (wx >= 0.0f) && (wx <= (float)(WW - 1));
    if (!inside) return;
    float ty = floorf(wy);
    float lx = floorf(wx);
    int base = b * NN;
#pragma unroll
    for (int k = 0; k < 4; ++k) {
        float ny = ty + (float)(k >> 1);
        float nx = lx + (float)(k & 1);
        int iy = (int)ny;
        int ix = (int)nx;
        if (iy < 0 || iy >= HH || ix < 0 || ix >= WW) continue;
        float wgt_y = fminf(fmaxf(1.0f - fabsf(wy - ny), 0.0f), 1.0f);
        float wgt_x = fminf(fmaxf(1.0f - fabsf(wx - nx), 0.0f), 1.0f);
        float w = wgt_y * wgt_x;
        int fi = base + iy * WW + ix;
        gatomic(&sum_w[fi],  w);
        gatomic(&sum_wy[fi], w * fy);
        gatomic(&sum_wx[fi], w * fx);
    }
}

__global__ void finalize_kernel(const float* __restrict__ sum_w,
                                const float* __restrict__ sum_wy,
                                const float* __restrict__ sum_wx,
                                float* __restrict__ out) {
    int t = blockIdx.x * blockDim.x + threadIdx.x;
    if (t >= BB * NN) return;
    float denom = sum_w[t] + EPS;
    out[t]                   = sum_wx[t] / denom;
    out[(size_t)BB * NN + t] = sum_wy[t] / denom;
}

// ---------------- launch ----------------

extern "C" void kernel_launch(void* const* d_in, const int* in_sizes, int n_in,
                              void* d_out, int out_size, void* d_ws, size_t ws_size,
                              hipStream_t stream) {
    const float* fx_all = (const float*)d_in[0];
    const float* fy_all = (const float*)d_in[1];
    const int* i_ptr    = (const int*)d_in[2];
    const int* tref_ptr = (const int*)d_in[3];
    float* out = (float*)d_out;

    const size_t BN = (size_t)BB * NN;   // 2.4576 M cells
    // ws layout: Sw|Swy|Swx|Fw|Fwy|Fwx = 6 planes
    if (ws_size >= 6 * BN * sizeof(float)) {
        float* Sw  = (float*)d_ws;
        float* Swy = Sw  + BN;
        float* Swx = Swy + BN;
        float* Fw  = Swx + BN;
        float* Fwy = Fw  + BN;
        float* Fwx = Fwy + BN;

        hipMemsetAsync(Fw, 0, 3 * BN * sizeof(float), stream);
        dim3 grid(NBX, NBY, BB);
        bin_gather_splat<<<grid, 256, 0, stream>>>(fx_all, fy_all, i_ptr, tref_ptr,
                                                   Sw, Swy, Swx, Fw, Fwy, Fwx);
        int total = (int)BN;
        merge_finalize<<<(total + 255) / 256, 256, 0, stream>>>(Sw, Swy, Swx,
                                                                Fw, Fwy, Fwx, out);
    } else {
        // R1 fallback: global-atomic splat (native adds)
        float* sum_w  = (float*)d_ws;
        float* sum_wy = sum_w + BN;
        float* sum_wx = sum_wy + BN;
        hipMemsetAsync(d_ws, 0, 3 * BN * sizeof(float), stream);
        int total = (int)BN;
        int block = 256;
        int grid1 = (total + block - 1) / block;
        splat_kernel<<<grid1, block, 0, stream>>>(fx_all, fy_all, i_ptr, tref_ptr,
                                                  sum_w, sum_wy, sum_wx);
        finalize_kernel<<<grid1, block, 0, stream>>>(sum_w, sum_wy, sum_wx, out);
    }
}